// Round 1
// baseline (148.558 us; speedup 1.0000x reference)
//
#include <hip/hip_runtime.h>
#include <math.h>

#define B_TOTAL 16384
#define F_TOTAL 256
#define H1 32
#define H2 16
#define FG 16    // features per block
#define BT 256   // batch elements per block (== blockDim.x)

// Each thread owns one batch element b; block handles FG consecutive features.
// Weight indices are wave-uniform -> compiler emits s_load (scalar pipe),
// inner FMAs are v_fmac_f32 vdst, sgpr, vgpr. No LDS needed.
__global__ __launch_bounds__(BT, 2) void nam_main(
    const float* __restrict__ x,   // [B, F]
    const float* __restrict__ W1,  // [F, 1, H1]
    const float* __restrict__ b1,  // [F, H1]
    const float* __restrict__ W2,  // [F, H1, H2]
    const float* __restrict__ b2,  // [F, H2]
    const float* __restrict__ W3,  // [F, H2, 1]
    const float* __restrict__ b3,  // [F, 1]
    float* __restrict__ acc)       // [B] fp32 accumulator (pre-zeroed)
{
    const int b  = blockIdx.x * BT + threadIdx.x;
    const int f0 = blockIdx.y * FG;

    // Load this thread's FG x values (f0 is a multiple of 16 -> 64B aligned).
    float xv[FG];
    const float4* xp = (const float4*)(x + (size_t)b * F_TOTAL + f0);
    #pragma unroll
    for (int i = 0; i < FG / 4; ++i) {
        float4 v = xp[i];
        xv[4*i+0] = v.x; xv[4*i+1] = v.y; xv[4*i+2] = v.z; xv[4*i+3] = v.w;
    }

    float acc_c = 0.0f;

    #pragma unroll 1
    for (int fi = 0; fi < FG; ++fi) {
        const int f = f0 + fi;
        const float xb = xv[fi];

        const float* w1f = W1 + (size_t)f * H1;
        const float* b1f = b1 + (size_t)f * H1;
        float h1v[H1];
        #pragma unroll
        for (int j = 0; j < H1; ++j) {
            float t = fmaf(xb, w1f[j], b1f[j]);
            h1v[j] = t > 0.0f ? t : 0.0f;
        }

        const float* b2f = b2 + (size_t)f * H2;
        float h2v[H2];
        #pragma unroll
        for (int k = 0; k < H2; ++k) h2v[k] = b2f[k];

        const float* w2f = W2 + (size_t)f * H1 * H2;
        #pragma unroll
        for (int j = 0; j < H1; ++j) {
            const float hj = h1v[j];
            #pragma unroll
            for (int k = 0; k < H2; ++k)
                h2v[k] = fmaf(hj, w2f[j * H2 + k], h2v[k]);
        }

        const float* w3f = W3 + (size_t)f * H2;
        float c = b3[f];
        #pragma unroll
        for (int k = 0; k < H2; ++k) {
            float h = h2v[k] > 0.0f ? h2v[k] : 0.0f;
            c = fmaf(h, w3f[k], c);
        }
        acc_c += c;
    }

    atomicAdd(&acc[b], acc_c);
}

__global__ __launch_bounds__(256) void nam_sigmoid(
    const float* __restrict__ acc, float* __restrict__ out)
{
    const int b = blockIdx.x * blockDim.x + threadIdx.x;
    const float s = acc[b];
    out[b] = 1.0f / (1.0f + expf(-s));
}

extern "C" void kernel_launch(void* const* d_in, const int* in_sizes, int n_in,
                              void* d_out, int out_size, void* d_ws, size_t ws_size,
                              hipStream_t stream) {
    const float* x  = (const float*)d_in[0];
    const float* W1 = (const float*)d_in[1];
    const float* b1 = (const float*)d_in[2];
    const float* W2 = (const float*)d_in[3];
    const float* b2 = (const float*)d_in[4];
    const float* W3 = (const float*)d_in[5];
    const float* b3 = (const float*)d_in[6];
    float* out = (float*)d_out;
    float* acc = (float*)d_ws;   // B_TOTAL floats = 64 KB scratch

    hipMemsetAsync(acc, 0, B_TOTAL * sizeof(float), stream);

    dim3 grid(B_TOTAL / BT, F_TOTAL / FG);
    nam_main<<<grid, BT, 0, stream>>>(x, W1, b1, W2, b2, W3, b3, acc);

    nam_sigmoid<<<B_TOTAL / 256, 256, 0, stream>>>(acc, out);
}